// Round 12
// baseline (155.277 us; speedup 1.0000x reference)
//
#include <hip/hip_runtime.h>

#define NF 40
#define KD 64

typedef float f32x4 __attribute__((ext_vector_type(4)));
typedef _Float16 f16x8 __attribute__((ext_vector_type(8)));
typedef _Float16 f16x4 __attribute__((ext_vector_type(4)));

// ---------- setup: precompute W1 (f16, fragment order) + pair LUT into d_ws
// ws layout: [0..4095] f16 w1h: idx = ((ks*4+lhi)*4+at)*16*8 + l15*8 + el
//            [4096..4927] u16 lut: p -> (i<<8|j)
__global__ __launch_bounds__(256)
void afm_setup(const float* __restrict__ W1, unsigned short* __restrict__ ws) {
    int tid = blockIdx.x * 256 + threadIdx.x;   // grid 8 -> 2048 threads
    for (int idx = tid; idx < 4096; idx += 2048) {
        int el = idx & 7, l15 = (idx >> 3) & 15, at = (idx >> 7) & 3,
            lhi = (idx >> 9) & 3, ks = idx >> 11;
        _Float16 h = (_Float16)W1[(ks * 32 + lhi * 8 + el) * KD + at * 16 + l15];
        ws[idx] = *(unsigned short*)&h;
    }
    for (int p0 = tid; p0 < 832; p0 += 2048) {
        int p = p0 > 819 ? 819 : p0;           // pad entries dup pair (39,39)
        int i = (int)((81.0f - sqrtf(6561.0f - 8.0f * (float)p)) * 0.5f);
        int off = (i * (81 - i)) >> 1;
        if ((((i + 1) * (80 - i)) >> 1) <= p) { ++i; off = (i * (81 - i)) >> 1; }
        else if (off > p)                     { --i; off = (i * (81 - i)) >> 1; }
        int j = i + (p - off);
        ws[4096 + p0] = (unsigned short)((i << 8) | j);
    }
}

__global__ __launch_bounds__(256, 8)
void afm_kernel(const int* __restrict__ x,
                const float* __restrict__ lin_table,
                const float* __restrict__ V_table,
                const unsigned short* __restrict__ ws,
                const float* __restrict__ b1,
                const float* __restrict__ W2,
                const float* __restrict__ Wf,
                const float* __restrict__ bf,
                float* __restrict__ out)
{
    // stride 72 f16 = 144 B: b128-aligned rows, 4-bank/row rotation
    __shared__ _Float16 e16[NF][72];    // embeddings rows 0..39
    __shared__ _Float16 Q16[NF][72];    // exp(score); cols 40..63 zero
    __shared__ unsigned short lut[832];
    __shared__ float zbuf[NF];
    __shared__ float webuf[4][KD];
    const int b = blockIdx.x;
    const int tid = threadIdx.x;
    const int w = tid >> 6;
    const int lane = tid & 63;
    const int l15 = lane & 15;
    const int lhi = lane >> 4;

    // ---- prologue: linv (wave0), LUT copy, Q16 col-pad zero, webuf zero
    float linv = 0.0f;
    if (w == 0 && lane < NF) linv = lin_table[x[b * NF + lane]];
    for (int t4 = tid; t4 < 416; t4 += 256)
        reinterpret_cast<unsigned*>(lut)[t4] =
            reinterpret_cast<const unsigned*>(ws + 4096)[t4];
    {
        f16x8 zh = {0, 0, 0, 0, 0, 0, 0, 0};
        if (tid < 120) {                       // rows 0..39, cols 40..63
            int r = tid / 3, cc = tid - r * 3;
            *reinterpret_cast<f16x8*>(&Q16[r][40 + 8 * cc]) = zh;
        }
        reinterpret_cast<float*>(webuf)[tid] = 0.0f;
    }

    // ---- Af from precomputed f16 ws: 8 coalesced 16B loads, zero VALU
    f16x8 Af[4][2];
    {
        const f16x8* w1v = reinterpret_cast<const f16x8*>(ws);
        #pragma unroll
        for (int at = 0; at < 4; ++at)
            #pragma unroll
            for (int ks = 0; ks < 2; ++ks)
                Af[at][ks] = w1v[((ks * 4 + lhi) * 4 + at) * 16 + l15];
    }
    f32x4 b1v[4], w2v[4];
    #pragma unroll
    for (int at = 0; at < 4; ++at) {
        #pragma unroll
        for (int r = 0; r < 4; ++r) {
            b1v[at][r] = b1[at * 16 + lhi * 4 + r];
            w2v[at][r] = W2[at * 16 + lhi * 4 + r];
        }
    }
    const float Wfv = Wf[lane];

    // ---- gather embeddings: coalesced float4 -> f16 rows
    for (int q = tid; q < NF * (KD / 4); q += 256) {
        int i = q >> 4;
        int k4 = q & 15;
        int ix = x[b * NF + i];
        float4 v = reinterpret_cast<const float4*>(V_table + (size_t)ix * KD)[k4];
        f16x4 hv = {(_Float16)v.x, (_Float16)v.y, (_Float16)v.z, (_Float16)v.w};
        *reinterpret_cast<f16x4*>(&e16[i][k4 * 4]) = hv;
    }
    __syncthreads();

    // ---- score GEMM over i<=j pairs (symmetric). 52 tiles of 16.
    for (int mt = w; mt < 52; mt += 4) {
        const int v = lut[mt * 16 + l15];
        const int i = v >> 8;
        const int j = v & 255;

        const _Float16* ei = &e16[i][0];
        const _Float16* ej = &e16[j][0];
        const int k0 = lhi * 8;
        f16x8 B0 = (*reinterpret_cast<const f16x8*>(ei + k0)) *
                   (*reinterpret_cast<const f16x8*>(ej + k0));
        f16x8 B1 = (*reinterpret_cast<const f16x8*>(ei + k0 + 32)) *
                   (*reinterpret_cast<const f16x8*>(ej + k0 + 32));

        f32x4 d[4];
        #pragma unroll
        for (int at = 0; at < 4; ++at) {
            d[at] = b1v[at];
            d[at] = __builtin_amdgcn_mfma_f32_16x16x32_f16(Af[at][0], B0, d[at], 0, 0, 0);
            d[at] = __builtin_amdgcn_mfma_f32_16x16x32_f16(Af[at][1], B1, d[at], 0, 0, 0);
        }

        float s = 0.0f;
        #pragma unroll
        for (int at = 0; at < 4; ++at) {
            #pragma unroll
            for (int r = 0; r < 4; ++r)
                s = fmaf(fmaxf(d[at][r], 0.0f), w2v[at][r], s);
        }
        s += __shfl_xor(s, 16, 64);
        s += __shfl_xor(s, 32, 64);
        // scores O(+-0.01): exp without max-shift safe; softmax shift-invariant.
        float qv = __expf(s);
        if (lhi == 0) {
            _Float16 qh = (_Float16)qv;
            Q16[i][j] = qh;                // mirror write: symmetric scores
            Q16[j][i] = qh;
        }
    }
    __syncthreads();

    // ---- PV via MFMA: G[i,c] = sum_j Q[i,j]*E[j,c]; nt==4 ones-col -> Z_i.
    f32x4 gd[4];
    #pragma unroll
    for (int it = 0; it < 4; ++it) gd[it] = (f32x4){0.f, 0.f, 0.f, 0.f};

    #pragma unroll
    for (int it = 0; it < 4; ++it) {
        const int t = w + it * 4;
        if (t < 15) {
            const int mt = (t * 52) >> 8;      // t/5, exact for t<15
            const int nt = t - mt * 5;

            const int arow = mt * 16 + l15;
            const int arc = arow > 39 ? 39 : arow;         // clamp addr
            const _Float16* qrow = &Q16[arc][0];
            f16x8 aq0 = *reinterpret_cast<const f16x8*>(qrow + lhi * 8);
            f16x8 aq1 = *reinterpret_cast<const f16x8*>(qrow + 32 + lhi * 8);
            if (arow > 39) {                               // pad rows -> 0
                f16x8 zh = {0, 0, 0, 0, 0, 0, 0, 0};
                aq0 = zh; aq1 = zh;
            }

            f16x8 bv0, bv1;
            if (nt == 4) {                     // ones column; j>=40 -> 0
                _Float16 one1 = (l15 == 0) ? (_Float16)1.0f : (_Float16)0.0f;
                #pragma unroll
                for (int el = 0; el < 8; ++el) {
                    bv0[el] = one1;                               // j = lhi*8+el < 40
                    bv1[el] = (lhi == 0) ? one1 : (_Float16)0.0f; // j = 32+lhi*8+el
                }
            } else {
                const int c = nt * 16 + l15;
                #pragma unroll
                for (int el = 0; el < 8; ++el) {
                    bv0[el] = e16[lhi * 8 + el][c];               // rows 0..31
                    bv1[el] = (lhi == 0) ? e16[32 + el][c]        // rows 32..39
                                         : (_Float16)0.0f;        // rows 40..63 = 0
                }
            }

            f32x4 dq = {0.f, 0.f, 0.f, 0.f};
            dq = __builtin_amdgcn_mfma_f32_16x16x32_f16(aq0, bv0, dq, 0, 0, 0);
            dq = __builtin_amdgcn_mfma_f32_16x16x32_f16(aq1, bv1, dq, 0, 0, 0);

            if (nt == 4) {
                #pragma unroll
                for (int r = 0; r < 4; ++r) {
                    int ii = mt * 16 + lhi * 4 + r;
                    if (l15 == 0 && ii < NF) zbuf[ii] = dq[r];
                }
            } else {
                gd[it] = dq;
            }
        }
    }
    __syncthreads();

    // ---- we[c] = sum_i e[i][c] * G[i,c] / Z_i  (rows ii>=40 have gd==0)
    #pragma unroll
    for (int it = 0; it < 4; ++it) {
        const int t = w + it * 4;
        if (t < 15) {
            const int mt = (t * 52) >> 8;
            const int nt = t - mt * 5;
            if (nt != 4) {
                const int c = nt * 16 + l15;
                float acc = 0.0f;
                #pragma unroll
                for (int r = 0; r < 4; ++r) {
                    int ii = mt * 16 + lhi * 4 + r;
                    int iic = ii > 39 ? 39 : ii;           // clamp reads; gd=0 there
                    float ev = (float)e16[iic][c];
                    acc = fmaf(ev * gd[it][r],
                               __builtin_amdgcn_rcpf(zbuf[iic]), acc);
                }
                acc += __shfl_xor(acc, 16, 64);
                acc += __shfl_xor(acc, 32, 64);
                if (lhi == 0) webuf[w][c] = acc;   // each (w,c) written once
            }
        }
    }
    __syncthreads();

    // ---- final: interaction dot + linear + sigmoid
    if (w == 0) {
        float we = webuf[0][lane] + webuf[1][lane] + webuf[2][lane] + webuf[3][lane];
        float c = fmaf(we, Wfv, linv);
        #pragma unroll
        for (int off = 32; off > 0; off >>= 1)
            c += __shfl_xor(c, off, 64);
        if (lane == 0) {
            float z = c + bf[0];
            out[b] = 1.0f / (1.0f + __expf(-z));
        }
    }
}

extern "C" void kernel_launch(void* const* d_in, const int* in_sizes, int n_in,
                              void* d_out, int out_size, void* d_ws, size_t ws_size,
                              hipStream_t stream) {
    const int*   x         = (const int*)d_in[0];
    const float* lin_table = (const float*)d_in[1];
    const float* V_table   = (const float*)d_in[2];
    const float* W1        = (const float*)d_in[3];
    const float* b1        = (const float*)d_in[4];
    const float* W2        = (const float*)d_in[5];
    const float* Wf        = (const float*)d_in[7];
    const float* bf        = (const float*)d_in[8];
    float* out = (float*)d_out;
    unsigned short* ws16 = (unsigned short*)d_ws;

    afm_setup<<<8, 256, 0, stream>>>(W1, ws16);
    const int batch = in_sizes[0] / NF;   // 2048
    afm_kernel<<<batch, 256, 0, stream>>>(x, lin_table, V_table, ws16, b1, W2,
                                          Wf, bf, out);
}

// Round 13
// 38.962 us; speedup vs baseline: 3.9853x; 3.9853x over previous
//
#include <hip/hip_runtime.h>

#define NF 40
#define KD 64

typedef float f32x4 __attribute__((ext_vector_type(4)));
typedef _Float16 f16x8 __attribute__((ext_vector_type(8)));
typedef _Float16 f16x4 __attribute__((ext_vector_type(4)));

// ---------- setup: precompute W1 (f16, fragment order) + pair LUT into d_ws
// ws layout: [0..4095] f16 w1h: idx = ((ks*4+lhi)*4+at)*16*8 + l15*8 + el
//            [4096..4927] u16 lut: p -> (i<<8|j)
__global__ __launch_bounds__(256)
void afm_setup(const float* __restrict__ W1, unsigned short* __restrict__ ws) {
    int tid = blockIdx.x * 256 + threadIdx.x;   // grid 8 -> 2048 threads
    for (int idx = tid; idx < 4096; idx += 2048) {
        int el = idx & 7, l15 = (idx >> 3) & 15, at = (idx >> 7) & 3,
            lhi = (idx >> 9) & 3, ks = idx >> 11;
        _Float16 h = (_Float16)W1[(ks * 32 + lhi * 8 + el) * KD + at * 16 + l15];
        ws[idx] = *(unsigned short*)&h;
    }
    for (int p0 = tid; p0 < 832; p0 += 2048) {
        int p = p0 > 819 ? 819 : p0;           // pad entries dup pair (39,39)
        int i = (int)((81.0f - sqrtf(6561.0f - 8.0f * (float)p)) * 0.5f);
        int off = (i * (81 - i)) >> 1;
        if ((((i + 1) * (80 - i)) >> 1) <= p) { ++i; off = (i * (81 - i)) >> 1; }
        else if (off > p)                     { --i; off = (i * (81 - i)) >> 1; }
        int j = i + (p - off);
        ws[4096 + p0] = (unsigned short)((i << 8) | j);
    }
}

__global__ __launch_bounds__(256, 4)   // R12 lesson: 8 waves/EU forces 32-VGPR spill hell
void afm_kernel(const int* __restrict__ x,
                const float* __restrict__ lin_table,
                const float* __restrict__ V_table,
                const unsigned short* __restrict__ ws,
                const float* __restrict__ b1,
                const float* __restrict__ W2,
                const float* __restrict__ Wf,
                const float* __restrict__ bf,
                float* __restrict__ out)
{
    // stride 72 f16 = 144 B: b128-aligned rows, 4-bank/row rotation
    __shared__ _Float16 e16[NF][72];    // embeddings rows 0..39
    __shared__ _Float16 Q16[NF][72];    // exp(score); cols 40..63 zero
    __shared__ unsigned short lut[832];
    __shared__ float zbuf[NF];
    __shared__ float webuf[4][KD];
    const int b = blockIdx.x;
    const int tid = threadIdx.x;
    const int w = tid >> 6;
    const int lane = tid & 63;
    const int l15 = lane & 15;
    const int lhi = lane >> 4;

    // ---- prologue: linv (wave0), LUT copy, Q16 col-pad zero, webuf zero
    float linv = 0.0f;
    if (w == 0 && lane < NF) linv = lin_table[x[b * NF + lane]];
    for (int t4 = tid; t4 < 416; t4 += 256)
        reinterpret_cast<unsigned*>(lut)[t4] =
            reinterpret_cast<const unsigned*>(ws + 4096)[t4];
    {
        f16x8 zh = {0, 0, 0, 0, 0, 0, 0, 0};
        if (tid < 120) {                       // rows 0..39, cols 40..63
            int r = tid / 3, cc = tid - r * 3;
            *reinterpret_cast<f16x8*>(&Q16[r][40 + 8 * cc]) = zh;
        }
        reinterpret_cast<float*>(webuf)[tid] = 0.0f;
    }

    // ---- Af from precomputed f16 ws: 8 coalesced 16B loads, zero VALU
    f16x8 Af[4][2];
    {
        const f16x8* w1v = reinterpret_cast<const f16x8*>(ws);
        #pragma unroll
        for (int at = 0; at < 4; ++at)
            #pragma unroll
            for (int ks = 0; ks < 2; ++ks)
                Af[at][ks] = w1v[((ks * 4 + lhi) * 4 + at) * 16 + l15];
    }
    f32x4 b1v[4], w2v[4];
    #pragma unroll
    for (int at = 0; at < 4; ++at) {
        #pragma unroll
        for (int r = 0; r < 4; ++r) {
            b1v[at][r] = b1[at * 16 + lhi * 4 + r];
            w2v[at][r] = W2[at * 16 + lhi * 4 + r];
        }
    }
    const float Wfv = Wf[lane];

    // ---- gather embeddings: coalesced float4 -> f16 rows
    for (int q = tid; q < NF * (KD / 4); q += 256) {
        int i = q >> 4;
        int k4 = q & 15;
        int ix = x[b * NF + i];
        float4 v = reinterpret_cast<const float4*>(V_table + (size_t)ix * KD)[k4];
        f16x4 hv = {(_Float16)v.x, (_Float16)v.y, (_Float16)v.z, (_Float16)v.w};
        *reinterpret_cast<f16x4*>(&e16[i][k4 * 4]) = hv;
    }
    __syncthreads();

    // ---- score GEMM over i<=j pairs (symmetric). 52 tiles of 16.
    for (int mt = w; mt < 52; mt += 4) {
        const int v = lut[mt * 16 + l15];
        const int i = v >> 8;
        const int j = v & 255;

        const _Float16* ei = &e16[i][0];
        const _Float16* ej = &e16[j][0];
        const int k0 = lhi * 8;
        f16x8 B0 = (*reinterpret_cast<const f16x8*>(ei + k0)) *
                   (*reinterpret_cast<const f16x8*>(ej + k0));
        f16x8 B1 = (*reinterpret_cast<const f16x8*>(ei + k0 + 32)) *
                   (*reinterpret_cast<const f16x8*>(ej + k0 + 32));

        f32x4 d[4];
        #pragma unroll
        for (int at = 0; at < 4; ++at) {
            d[at] = b1v[at];
            d[at] = __builtin_amdgcn_mfma_f32_16x16x32_f16(Af[at][0], B0, d[at], 0, 0, 0);
            d[at] = __builtin_amdgcn_mfma_f32_16x16x32_f16(Af[at][1], B1, d[at], 0, 0, 0);
        }

        float s = 0.0f;
        #pragma unroll
        for (int at = 0; at < 4; ++at) {
            #pragma unroll
            for (int r = 0; r < 4; ++r)
                s = fmaf(fmaxf(d[at][r], 0.0f), w2v[at][r], s);
        }
        s += __shfl_xor(s, 16, 64);
        s += __shfl_xor(s, 32, 64);
        // scores O(+-0.01): exp without max-shift safe; softmax shift-invariant.
        float qv = __expf(s);
        if (lhi == 0) {
            _Float16 qh = (_Float16)qv;
            Q16[i][j] = qh;                // mirror write: symmetric scores
            Q16[j][i] = qh;
        }
    }
    __syncthreads();

    // ---- PV via MFMA: G[i,c] = sum_j Q[i,j]*E[j,c]; nt==4 ones-col -> Z_i.
    f32x4 gd[4];
    #pragma unroll
    for (int it = 0; it < 4; ++it) gd[it] = (f32x4){0.f, 0.f, 0.f, 0.f};

    #pragma unroll
    for (int it = 0; it < 4; ++it) {
        const int t = w + it * 4;
        if (t < 15) {
            const int mt = (t * 52) >> 8;      // t/5, exact for t<15
            const int nt = t - mt * 5;

            const int arow = mt * 16 + l15;
            const int arc = arow > 39 ? 39 : arow;         // clamp addr
            const _Float16* qrow = &Q16[arc][0];
            f16x8 aq0 = *reinterpret_cast<const f16x8*>(qrow + lhi * 8);
            f16x8 aq1 = *reinterpret_cast<const f16x8*>(qrow + 32 + lhi * 8);
            if (arow > 39) {                               // pad rows -> 0
                f16x8 zh = {0, 0, 0, 0, 0, 0, 0, 0};
                aq0 = zh; aq1 = zh;
            }

            f16x8 bv0, bv1;
            if (nt == 4) {                     // ones column; j>=40 -> 0
                _Float16 one1 = (l15 == 0) ? (_Float16)1.0f : (_Float16)0.0f;
                #pragma unroll
                for (int el = 0; el < 8; ++el) {
                    bv0[el] = one1;                               // j = lhi*8+el < 40
                    bv1[el] = (lhi == 0) ? one1 : (_Float16)0.0f; // j = 32+lhi*8+el
                }
            } else {
                const int c = nt * 16 + l15;
                #pragma unroll
                for (int el = 0; el < 8; ++el) {
                    bv0[el] = e16[lhi * 8 + el][c];               // rows 0..31
                    bv1[el] = (lhi == 0) ? e16[32 + el][c]        // rows 32..39
                                         : (_Float16)0.0f;        // rows 40..63 = 0
                }
            }

            f32x4 dq = {0.f, 0.f, 0.f, 0.f};
            dq = __builtin_amdgcn_mfma_f32_16x16x32_f16(aq0, bv0, dq, 0, 0, 0);
            dq = __builtin_amdgcn_mfma_f32_16x16x32_f16(aq1, bv1, dq, 0, 0, 0);

            if (nt == 4) {
                #pragma unroll
                for (int r = 0; r < 4; ++r) {
                    int ii = mt * 16 + lhi * 4 + r;
                    if (l15 == 0 && ii < NF) zbuf[ii] = dq[r];
                }
            } else {
                gd[it] = dq;
            }
        }
    }
    __syncthreads();

    // ---- we[c] = sum_i e[i][c] * G[i,c] / Z_i  (rows ii>=40 have gd==0)
    #pragma unroll
    for (int it = 0; it < 4; ++it) {
        const int t = w + it * 4;
        if (t < 15) {
            const int mt = (t * 52) >> 8;
            const int nt = t - mt * 5;
            if (nt != 4) {
                const int c = nt * 16 + l15;
                float acc = 0.0f;
                #pragma unroll
                for (int r = 0; r < 4; ++r) {
                    int ii = mt * 16 + lhi * 4 + r;
                    int iic = ii > 39 ? 39 : ii;           // clamp reads; gd=0 there
                    float ev = (float)e16[iic][c];
                    acc = fmaf(ev * gd[it][r],
                               __builtin_amdgcn_rcpf(zbuf[iic]), acc);
                }
                acc += __shfl_xor(acc, 16, 64);
                acc += __shfl_xor(acc, 32, 64);
                if (lhi == 0) webuf[w][c] = acc;   // each (w,c) written once
            }
        }
    }
    __syncthreads();

    // ---- final: interaction dot + linear + sigmoid
    if (w == 0) {
        float we = webuf[0][lane] + webuf[1][lane] + webuf[2][lane] + webuf[3][lane];
        float c = fmaf(we, Wfv, linv);
        #pragma unroll
        for (int off = 32; off > 0; off >>= 1)
            c += __shfl_xor(c, off, 64);
        if (lane == 0) {
            float z = c + bf[0];
            out[b] = 1.0f / (1.0f + __expf(-z));
        }
    }
}

extern "C" void kernel_launch(void* const* d_in, const int* in_sizes, int n_in,
                              void* d_out, int out_size, void* d_ws, size_t ws_size,
                              hipStream_t stream) {
    const int*   x         = (const int*)d_in[0];
    const float* lin_table = (const float*)d_in[1];
    const float* V_table   = (const float*)d_in[2];
    const float* W1        = (const float*)d_in[3];
    const float* b1        = (const float*)d_in[4];
    const float* W2        = (const float*)d_in[5];
    const float* Wf        = (const float*)d_in[7];
    const float* bf        = (const float*)d_in[8];
    float* out = (float*)d_out;
    unsigned short* ws16 = (unsigned short*)d_ws;

    afm_setup<<<8, 256, 0, stream>>>(W1, ws16);
    const int batch = in_sizes[0] / NF;   // 2048
    afm_kernel<<<batch, 256, 0, stream>>>(x, lin_table, V_table, ws16, b1, W2,
                                          Wf, bf, out);
}

// Round 15
// 37.980 us; speedup vs baseline: 4.0884x; 1.0259x over previous
//
#include <hip/hip_runtime.h>

#define NF 40
#define KD 64

typedef float f32x4 __attribute__((ext_vector_type(4)));
typedef _Float16 f16x8 __attribute__((ext_vector_type(8)));
typedef _Float16 f16x4 __attribute__((ext_vector_type(4)));

__global__ __launch_bounds__(256, 4)
void afm_kernel(const int* __restrict__ x,
                const float* __restrict__ lin_table,
                const float* __restrict__ V_table,
                const float* __restrict__ W1,
                const float* __restrict__ b1,
                const float* __restrict__ W2,
                const float* __restrict__ b2,
                const float* __restrict__ Wf,
                const float* __restrict__ bf,
                float* __restrict__ out)
{
    // stride 72 f16 = 144 B: b128-aligned rows, 4-bank/row rotation
    __shared__ _Float16 e16[64][72];    // embeddings; rows 40..63 zero (PV K-pad)
    __shared__ _Float16 Q16[48][72];    // exp(score); pads zero
    __shared__ unsigned short lut[832]; // p -> (i<<8|j), triangular pairs
    __shared__ float zbuf[48];
    __shared__ float webuf[4][KD];
    __shared__ float linbuf[64];

    const int b = blockIdx.x;
    const int tid = threadIdx.x;
    const int w = tid >> 6;
    const int lane = tid & 63;
    const int l15 = lane & 15;
    const int lhi = lane >> 4;

    // ---- zero pads + build pair LUT (overlaps gather latency)
    {
        f16x8 zh = {0, 0, 0, 0, 0, 0, 0, 0};
        for (int t = tid; t < 48 * 72 / 8; t += 256)           // all of Q16
            reinterpret_cast<f16x8*>(&Q16[0][0])[t] = zh;
        if (tid < 216)                                         // e16 rows 40..63
            reinterpret_cast<f16x8*>(&e16[40][0])[tid] = zh;
        if (tid < 48) zbuf[tid] = 1.0f;
        reinterpret_cast<float*>(webuf)[tid] = 0.0f;
    }
    for (int p0 = tid; p0 < 832; p0 += 256) {
        int p = p0 > 819 ? 819 : p0;       // pad entries dup pair (39,39)
        int i = (int)((81.0f - sqrtf(6561.0f - 8.0f * (float)p)) * 0.5f);
        int off = (i * (81 - i)) >> 1;
        if ((((i + 1) * (80 - i)) >> 1) <= p) { ++i; off = (i * (81 - i)) >> 1; }
        else if (off > p)                   { --i; off = (i * (81 - i)) >> 1; }
        int j = i + (p - off);
        lut[p0] = (unsigned short)((i << 8) | j);
    }

    // ---- A fragments for score GEMM: W1^T (a x k), f16. D[a,p] orientation.
    f16x8 Af[4][2];
    #pragma unroll
    for (int at = 0; at < 4; ++at) {
        #pragma unroll
        for (int ks = 0; ks < 2; ++ks) {
            f16x8 t;
            #pragma unroll
            for (int el = 0; el < 8; ++el)
                t[el] = (_Float16)W1[(ks * 32 + lhi * 8 + el) * KD + at * 16 + l15];
            Af[at][ks] = t;
        }
    }
    f32x4 b1v[4], w2v[4];
    #pragma unroll
    for (int at = 0; at < 4; ++at) {
        #pragma unroll
        for (int r = 0; r < 4; ++r) {
            b1v[at][r] = b1[at * 16 + lhi * 4 + r];
            w2v[at][r] = W2[at * 16 + lhi * 4 + r];
        }
    }
    const float Wfv = Wf[lane];

    // ---- gather embeddings: coalesced float4 -> f16 rows
    for (int q = tid; q < NF * (KD / 4); q += 256) {
        int i = q >> 4;
        int k4 = q & 15;
        int ix = x[b * NF + i];
        float4 v = reinterpret_cast<const float4*>(V_table + (size_t)ix * KD)[k4];
        f16x4 hv = {(_Float16)v.x, (_Float16)v.y, (_Float16)v.z, (_Float16)v.w};
        *reinterpret_cast<f16x4*>(&e16[i][k4 * 4]) = hv;
    }
    if (tid < 64) linbuf[tid] = (tid < NF) ? lin_table[x[b * NF + tid]] : 0.0f;
    __syncthreads();

    // ---- score GEMM over i<=j pairs (symmetric), 52 tiles of 16.
    // 2-stage software pipeline: raw B-operands for tile n loaded during
    // tile n-1's compute; lut read 2 tiles ahead. Hides ~240cyc LDS latency.
    const int k0 = lhi * 8;
    int vc = lut[w * 16 + l15];            // tile mt = w
    f16x8 rei0, rei1, rej0, rej1;
    {
        const _Float16* ei = &e16[vc >> 8][0];
        const _Float16* ej = &e16[vc & 255][0];
        rei0 = *reinterpret_cast<const f16x8*>(ei + k0);
        rei1 = *reinterpret_cast<const f16x8*>(ei + k0 + 32);
        rej0 = *reinterpret_cast<const f16x8*>(ej + k0);
        rej1 = *reinterpret_cast<const f16x8*>(ej + k0 + 32);
    }
    int vn = lut[(w + 4) * 16 + l15];      // tile mt = w+4 (always < 52)

    for (int mt = w; mt < 52; mt += 4) {
        // current tile's indices + products (loads issued last iteration)
        const int i = vc >> 8;
        const int j = vc & 255;
        f16x8 B0 = rei0 * rej0;
        f16x8 B1 = rei1 * rej1;

        // issue NEXT tile's raw loads + next-next lut read
        if (mt + 4 < 52) {
            const _Float16* nei = &e16[vn >> 8][0];
            const _Float16* nej = &e16[vn & 255][0];
            rei0 = *reinterpret_cast<const f16x8*>(nei + k0);
            rei1 = *reinterpret_cast<const f16x8*>(nei + k0 + 32);
            rej0 = *reinterpret_cast<const f16x8*>(nej + k0);
            rej1 = *reinterpret_cast<const f16x8*>(nej + k0 + 32);
        }
        vc = vn;
        vn = (mt + 8 < 52) ? lut[(mt + 8) * 16 + l15] : vn;

        f32x4 d[4];
        #pragma unroll
        for (int at = 0; at < 4; ++at) {
            d[at] = b1v[at];
            d[at] = __builtin_amdgcn_mfma_f32_16x16x32_f16(Af[at][0], B0, d[at], 0, 0, 0);
            d[at] = __builtin_amdgcn_mfma_f32_16x16x32_f16(Af[at][1], B1, d[at], 0, 0, 0);
        }

        float s = 0.0f;
        #pragma unroll
        for (int at = 0; at < 4; ++at) {
            #pragma unroll
            for (int r = 0; r < 4; ++r)
                s = fmaf(fmaxf(d[at][r], 0.0f), w2v[at][r], s);
        }
        s += __shfl_xor(s, 16, 64);
        s += __shfl_xor(s, 32, 64);
        // scores O(+-0.01): exp without max-shift safe; softmax shift-invariant.
        float qv = __expf(s);
        if (lhi == 0) {
            _Float16 qh = (_Float16)qv;
            Q16[i][j] = qh;                // mirror write: symmetric scores
            Q16[j][i] = qh;
        }
    }
    __syncthreads();

    // ---- PV via MFMA: G[i,c] = sum_j Q[i,j]*E[j,c]; nt==4 ones-col -> Z_i.
    f32x4 gd[4];
    #pragma unroll
    for (int it = 0; it < 4; ++it) gd[it] = (f32x4){0.f, 0.f, 0.f, 0.f};

    #pragma unroll
    for (int it = 0; it < 4; ++it) {
        const int t = w + it * 4;
        if (t < 15) {
            const int mt = (t * 52) >> 8;      // t/5, exact for t<15
            const int nt = t - mt * 5;

            const _Float16* qrow = &Q16[mt * 16 + l15][0];
            f16x8 aq0 = *reinterpret_cast<const f16x8*>(qrow + lhi * 8);
            f16x8 aq1 = *reinterpret_cast<const f16x8*>(qrow + 32 + lhi * 8);

            f16x8 bv0, bv1;
            if (nt == 4) {                     // ones column; j>=40 -> 0
                _Float16 one1 = (l15 == 0) ? (_Float16)1.0f : (_Float16)0.0f;
                #pragma unroll
                for (int el = 0; el < 8; ++el) {
                    bv0[el] = one1;                               // j = lhi*8+el < 40
                    bv1[el] = (lhi == 0) ? one1 : (_Float16)0.0f; // j = 32+lhi*8+el
                }
            } else {
                const int c = nt * 16 + l15;
                #pragma unroll
                for (int el = 0; el < 8; ++el) {
                    bv0[el] = e16[lhi * 8 + el][c];
                    bv1[el] = e16[32 + lhi * 8 + el][c];
                }
            }

            f32x4 dq = {0.f, 0.f, 0.f, 0.f};
            dq = __builtin_amdgcn_mfma_f32_16x16x32_f16(aq0, bv0, dq, 0, 0, 0);
            dq = __builtin_amdgcn_mfma_f32_16x16x32_f16(aq1, bv1, dq, 0, 0, 0);

            if (nt == 4) {
                #pragma unroll
                for (int r = 0; r < 4; ++r) {
                    int ii = mt * 16 + lhi * 4 + r;
                    if (l15 == 0 && ii < 40) zbuf[ii] = dq[r];
                }
            } else {
                gd[it] = dq;
            }
        }
    }
    __syncthreads();

    // ---- we[c] = sum_i e[i][c] * G[i,c] / Z_i   (pad rows contribute 0)
    #pragma unroll
    for (int it = 0; it < 4; ++it) {
        const int t = w + it * 4;
        if (t < 15) {
            const int mt = (t * 52) >> 8;
            const int nt = t - mt * 5;
            if (nt != 4) {
                const int c = nt * 16 + l15;
                float acc = 0.0f;
                #pragma unroll
                for (int r = 0; r < 4; ++r) {
                    int ii = mt * 16 + lhi * 4 + r;
                    int iic = ii > 39 ? 39 : ii;   // clamp reads; gd=0 there
                    float ev = (float)e16[iic][c];
                    acc = fmaf(ev * gd[it][r],
                               __builtin_amdgcn_rcpf(zbuf[iic]), acc);
                }
                acc += __shfl_xor(acc, 16, 64);
                acc += __shfl_xor(acc, 32, 64);
                if (lhi == 0) webuf[w][c] = acc;   // each (w,c) written once
            }
        }
    }
    __syncthreads();

    // ---- final: interaction dot + linear + sigmoid
    if (w == 0) {
        float we = webuf[0][lane] + webuf[1][lane] + webuf[2][lane] + webuf[3][lane];
        float c = fmaf(we, Wfv, linbuf[lane]);
        #pragma unroll
        for (int off = 32; off > 0; off >>= 1)
            c += __shfl_xor(c, off, 64);
        if (lane == 0) {
            float z = c + bf[0];
            out[b] = 1.0f / (1.0f + __expf(-z));
        }
    }
}

extern "C" void kernel_launch(void* const* d_in, const int* in_sizes, int n_in,
                              void* d_out, int out_size, void* d_ws, size_t ws_size,
                              hipStream_t stream) {
    const int*   x         = (const int*)d_in[0];
    const float* lin_table = (const float*)d_in[1];
    const float* V_table   = (const float*)d_in[2];
    const float* W1        = (const float*)d_in[3];
    const float* b1        = (const float*)d_in[4];
    const float* W2        = (const float*)d_in[5];
    const float* b2        = (const float*)d_in[6];
    const float* Wf        = (const float*)d_in[7];
    const float* bf        = (const float*)d_in[8];
    float* out = (float*)d_out;

    const int batch = in_sizes[0] / NF;   // 2048
    afm_kernel<<<batch, 256, 0, stream>>>(x, lin_table, V_table, W1, b1, W2, b2,
                                          Wf, bf, out);
}

// Round 16
// 36.166 us; speedup vs baseline: 4.2935x; 1.0501x over previous
//
#include <hip/hip_runtime.h>

#define NF 40
#define KD 64

typedef float f32x4 __attribute__((ext_vector_type(4)));
typedef _Float16 f16x8 __attribute__((ext_vector_type(8)));
typedef _Float16 f16x4 __attribute__((ext_vector_type(4)));

__global__ __launch_bounds__(256, 4)
void afm_kernel(const int* __restrict__ x,
                const float* __restrict__ lin_table,
                const float* __restrict__ V_table,
                const float* __restrict__ W1,
                const float* __restrict__ b1,
                const float* __restrict__ W2,
                const float* __restrict__ b2,
                const float* __restrict__ Wf,
                const float* __restrict__ bf,
                float* __restrict__ out)
{
    // stride 72 f16 = 144 B: b128-aligned rows, 4-bank/row rotation
    __shared__ _Float16 e16[64][72];    // embeddings; rows 40..63 zero (PV K-pad)
    __shared__ _Float16 Q16[48][72];    // exp(score); pads zero
    __shared__ _Float16 W1T[64][72];    // W1 transposed [a][k], f16
    __shared__ unsigned short lut[832]; // p -> (i<<8|j), triangular pairs
    __shared__ float zbuf[48];
    __shared__ float webuf[4][KD];
    __shared__ float linbuf[64];

    const int b = blockIdx.x;
    const int tid = threadIdx.x;
    const int w = tid >> 6;
    const int lane = tid & 63;
    const int l15 = lane & 15;
    const int lhi = lane >> 4;

    // ---- zero pads + build pair LUT (overlaps gather latency)
    {
        f16x8 zh = {0, 0, 0, 0, 0, 0, 0, 0};
        for (int t = tid; t < 48 * 72 / 8; t += 256)           // all of Q16
            reinterpret_cast<f16x8*>(&Q16[0][0])[t] = zh;
        if (tid < 216)                                         // e16 rows 40..63
            reinterpret_cast<f16x8*>(&e16[40][0])[tid] = zh;
        if (tid < 48) zbuf[tid] = 1.0f;
        reinterpret_cast<float*>(webuf)[tid] = 0.0f;
    }
    for (int p0 = tid; p0 < 832; p0 += 256) {
        int p = p0 > 819 ? 819 : p0;       // pad entries dup pair (39,39)
        int i = (int)((81.0f - sqrtf(6561.0f - 8.0f * (float)p)) * 0.5f);
        int off = (i * (81 - i)) >> 1;
        if ((((i + 1) * (80 - i)) >> 1) <= p) { ++i; off = (i * (81 - i)) >> 1; }
        else if (off > p)                   { --i; off = (i * (81 - i)) >> 1; }
        int j = i + (p - off);
        lut[p0] = (unsigned short)((i << 8) | j);
    }

    // ---- cooperative W1 -> W1T staging (f32x4 coalesced, f16 transposed store)
    // thread q: k = q>>4, a4 = q&15 -> W1[k][4a4..4a4+3] -> W1T[4a4+m][k]
    for (int q = tid; q < KD * (KD / 4); q += 256) {
        int k = q >> 4;
        int a4 = q & 15;
        float4 v = reinterpret_cast<const float4*>(W1 + (size_t)k * KD)[a4];
        W1T[a4 * 4 + 0][k] = (_Float16)v.x;
        W1T[a4 * 4 + 1][k] = (_Float16)v.y;
        W1T[a4 * 4 + 2][k] = (_Float16)v.z;
        W1T[a4 * 4 + 3][k] = (_Float16)v.w;
    }

    // ---- b1/W2 epilogue constants: vector loads (16B aligned)
    f32x4 b1v[4], w2v[4];
    #pragma unroll
    for (int at = 0; at < 4; ++at) {
        b1v[at] = *reinterpret_cast<const f32x4*>(b1 + at * 16 + lhi * 4);
        w2v[at] = *reinterpret_cast<const f32x4*>(W2 + at * 16 + lhi * 4);
    }
    const float Wfv = Wf[lane];

    // ---- gather embeddings: coalesced float4 -> f16 rows
    for (int q = tid; q < NF * (KD / 4); q += 256) {
        int i = q >> 4;
        int k4 = q & 15;
        int ix = x[b * NF + i];
        float4 v = reinterpret_cast<const float4*>(V_table + (size_t)ix * KD)[k4];
        f16x4 hv = {(_Float16)v.x, (_Float16)v.y, (_Float16)v.z, (_Float16)v.w};
        *reinterpret_cast<f16x4*>(&e16[i][k4 * 4]) = hv;
    }
    if (tid < 64) linbuf[tid] = (tid < NF) ? lin_table[x[b * NF + tid]] : 0.0f;
    __syncthreads();

    // ---- A fragments from W1T: 8 ds_read_b128 (was 64 scalar global loads)
    f16x8 Af[4][2];
    #pragma unroll
    for (int at = 0; at < 4; ++at)
        #pragma unroll
        for (int ks = 0; ks < 2; ++ks)
            Af[at][ks] = *reinterpret_cast<const f16x8*>(
                &W1T[at * 16 + l15][ks * 32 + lhi * 8]);

    // ---- score GEMM over i<=j pairs (symmetric), 52 tiles of 16.
    const int k0 = lhi * 8;
    for (int mt = w; mt < 52; mt += 4) {
        const int v = lut[mt * 16 + l15];
        const int i = v >> 8;
        const int j = v & 255;

        const _Float16* ei = &e16[i][0];
        const _Float16* ej = &e16[j][0];
        f16x8 B0 = (*reinterpret_cast<const f16x8*>(ei + k0)) *
                   (*reinterpret_cast<const f16x8*>(ej + k0));
        f16x8 B1 = (*reinterpret_cast<const f16x8*>(ei + k0 + 32)) *
                   (*reinterpret_cast<const f16x8*>(ej + k0 + 32));

        f32x4 d[4];
        #pragma unroll
        for (int at = 0; at < 4; ++at) {
            d[at] = b1v[at];
            d[at] = __builtin_amdgcn_mfma_f32_16x16x32_f16(Af[at][0], B0, d[at], 0, 0, 0);
            d[at] = __builtin_amdgcn_mfma_f32_16x16x32_f16(Af[at][1], B1, d[at], 0, 0, 0);
        }

        float s = 0.0f;
        #pragma unroll
        for (int at = 0; at < 4; ++at) {
            #pragma unroll
            for (int r = 0; r < 4; ++r)
                s = fmaf(fmaxf(d[at][r], 0.0f), w2v[at][r], s);
        }
        s += __shfl_xor(s, 16, 64);
        s += __shfl_xor(s, 32, 64);
        // scores O(+-0.01): exp without max-shift safe; softmax shift-invariant.
        float qv = __expf(s);
        if (lhi == 0) {
            _Float16 qh = (_Float16)qv;
            Q16[i][j] = qh;                // mirror write: symmetric scores
            Q16[j][i] = qh;
        }
    }
    __syncthreads();

    // ---- PV via MFMA: G[i,c] = sum_j Q[i,j]*E[j,c]; nt==4 ones-col -> Z_i.
    f32x4 gd[4];
    #pragma unroll
    for (int it = 0; it < 4; ++it) gd[it] = (f32x4){0.f, 0.f, 0.f, 0.f};

    #pragma unroll
    for (int it = 0; it < 4; ++it) {
        const int t = w + it * 4;
        if (t < 15) {
            const int mt = (t * 52) >> 8;      // t/5, exact for t<15
            const int nt = t - mt * 5;

            const _Float16* qrow = &Q16[mt * 16 + l15][0];
            f16x8 aq0 = *reinterpret_cast<const f16x8*>(qrow + lhi * 8);
            f16x8 aq1 = *reinterpret_cast<const f16x8*>(qrow + 32 + lhi * 8);

            f16x8 bv0, bv1;
            if (nt == 4) {                     // ones column; j>=40 -> 0
                _Float16 one1 = (l15 == 0) ? (_Float16)1.0f : (_Float16)0.0f;
                #pragma unroll
                for (int el = 0; el < 8; ++el) {
                    bv0[el] = one1;                               // j = lhi*8+el < 40
                    bv1[el] = (lhi == 0) ? one1 : (_Float16)0.0f; // j = 32+lhi*8+el
                }
            } else {
                const int c = nt * 16 + l15;
                #pragma unroll
                for (int el = 0; el < 8; ++el) {
                    bv0[el] = e16[lhi * 8 + el][c];
                    bv1[el] = e16[32 + lhi * 8 + el][c];
                }
            }

            f32x4 dq = {0.f, 0.f, 0.f, 0.f};
            dq = __builtin_amdgcn_mfma_f32_16x16x32_f16(aq0, bv0, dq, 0, 0, 0);
            dq = __builtin_amdgcn_mfma_f32_16x16x32_f16(aq1, bv1, dq, 0, 0, 0);

            if (nt == 4) {
                #pragma unroll
                for (int r = 0; r < 4; ++r) {
                    int ii = mt * 16 + lhi * 4 + r;
                    if (l15 == 0 && ii < 40) zbuf[ii] = dq[r];
                }
            } else {
                gd[it] = dq;
            }
        }
    }
    __syncthreads();

    // ---- we[c] = sum_i e[i][c] * G[i,c] / Z_i   (pad rows contribute 0)
    #pragma unroll
    for (int it = 0; it < 4; ++it) {
        const int t = w + it * 4;
        if (t < 15) {
            const int mt = (t * 52) >> 8;
            const int nt = t - mt * 5;
            if (nt != 4) {
                const int c = nt * 16 + l15;
                float acc = 0.0f;
                #pragma unroll
                for (int r = 0; r < 4; ++r) {
                    int ii = mt * 16 + lhi * 4 + r;
                    int iic = ii > 39 ? 39 : ii;   // clamp reads; gd=0 there
                    float ev = (float)e16[iic][c];
                    acc = fmaf(ev * gd[it][r],
                               __builtin_amdgcn_rcpf(zbuf[iic]), acc);
                }
                acc += __shfl_xor(acc, 16, 64);
                acc += __shfl_xor(acc, 32, 64);
                if (lhi == 0) webuf[w][c] = acc;   // each (w,c) written once
            }
        }
    }
    __syncthreads();

    // ---- final: interaction dot + linear + sigmoid
    if (w == 0) {
        float we = webuf[0][lane] + webuf[1][lane] + webuf[2][lane] + webuf[3][lane];
        float c = fmaf(we, Wfv, linbuf[lane]);
        #pragma unroll
        for (int off = 32; off > 0; off >>= 1)
            c += __shfl_xor(c, off, 64);
        if (lane == 0) {
            float z = c + bf[0];
            out[b] = 1.0f / (1.0f + __expf(-z));
        }
    }
}

extern "C" void kernel_launch(void* const* d_in, const int* in_sizes, int n_in,
                              void* d_out, int out_size, void* d_ws, size_t ws_size,
                              hipStream_t stream) {
    const int*   x         = (const int*)d_in[0];
    const float* lin_table = (const float*)d_in[1];
    const float* V_table   = (const float*)d_in[2];
    const float* W1        = (const float*)d_in[3];
    const float* b1        = (const float*)d_in[4];
    const float* W2        = (const float*)d_in[5];
    const float* b2        = (const float*)d_in[6];
    const float* Wf        = (const float*)d_in[7];
    const float* bf        = (const float*)d_in[8];
    float* out = (float*)d_out;

    const int batch = in_sizes[0] / NF;   // 2048
    afm_kernel<<<batch, 256, 0, stream>>>(x, lin_table, V_table, W1, b1, W2, b2,
                                          Wf, bf, out);
}